// Round 1
// baseline (3171.123 us; speedup 1.0000x reference)
//
#include <hip/hip_runtime.h>
#include <math.h>

#define DIM 128

// ---------------------------------------------------------------------------
// Kernel 1: degree histogram (deg_out from src, deg_in from dst), as floats.
__global__ __launch_bounds__(256) void deg_kernel(const int* __restrict__ src,
                                                  const int* __restrict__ dst,
                                                  float* degO, float* degI, int E) {
    int e = blockIdx.x * 256 + threadIdx.x;
    if (e < E) {
        atomicAdd(&degO[src[e]], 1.0f);
        atomicAdd(&degI[dst[e]], 1.0f);
    }
}

// Kernel 2: deg -> rsqrt(max(deg,1)) in place, over both arrays (2N elems).
__global__ __launch_bounds__(256) void norm_kernel(float* d, int n2) {
    int i = blockIdx.x * 256 + threadIdx.x;
    if (i < n2) d[i] = rsqrtf(fmaxf(d[i], 1.0f));
}

// ---------------------------------------------------------------------------
// Kernel 3: edge scatter. One wave (64 lanes) per edge.
// agg row layout: [node][256]: cols 0..127 = feat-agg, 128..255 = hx-agg.
// lanes 0..31 handle the feat row (one float4 each), lanes 32..63 the hx row.
__global__ __launch_bounds__(256) void scatter_kernel(const float4* __restrict__ feat4,
                                                      const float4* __restrict__ hx4,
                                                      const int* __restrict__ src,
                                                      const int* __restrict__ dst,
                                                      const float* __restrict__ normO,
                                                      float* __restrict__ agg, int E) {
    int e = blockIdx.x * 4 + (threadIdx.x >> 6);
    if (e >= E) return;
    int lane = threadIdx.x & 63;
    int s = src[e];
    int d = dst[e];
    float ns = normO[s];
    int half = lane >> 5;
    int j = lane & 31;
    float4 v = (half ? hx4 : feat4)[(size_t)s * 32 + j];
    float* p = agg + (size_t)d * 256 + half * 128 + j * 4;
    atomicAdd(p + 0, v.x * ns);
    atomicAdd(p + 1, v.y * ns);
    atomicAdd(p + 2, v.z * ns);
    atomicAdd(p + 3, v.w * ns);
}

// ---------------------------------------------------------------------------
// Kernel 4: fused (norm_dst scale) + GEMM (i = aggf@Wi+bi, h = aggh@Wh+bh)
// + GRU gates + output.
// Block: 256 threads = 16 col-threads (tc) x 16 row-groups (tr, 2 rows each).
// Tile: 32 node-rows x 16 output-cols. Grid: (ceil(N/32), 8).
// LDS: sA[32 rows][64 float4-slots] XOR-swizzled (32KB)
//      sW[96 rows][32 float4-slots] XOR-swizzled (48KB) -> 80KB, 2 blocks/CU.
__global__ __launch_bounds__(256) void gemm_gates_kernel(
    const float* __restrict__ agg, const float* __restrict__ normI,
    const float* __restrict__ Wi, const float* __restrict__ bi,
    const float* __restrict__ Wh, const float* __restrict__ bh,
    const float* __restrict__ hx, float* __restrict__ out, int N) {
    __shared__ float4 sA[32 * 64];
    __shared__ float4 sW[96 * 32];

    const int tid = threadIdx.x;
    const int nb = blockIdx.x;   // node-row tile
    const int cb = blockIdx.y;   // 16-col tile within 0..127

    // --- stage A: 32 rows x 256 floats (both halves), scaled by norm_dst ---
    const float4* agg4 = (const float4*)agg;
#pragma unroll
    for (int i = 0; i < 8; ++i) {
        int f = i * 256 + tid;
        int r = f >> 6;          // 0..31
        int x4 = f & 63;         // 0..63 float4 within row
        int row = nb * 32 + r;
        float4 v = make_float4(0.f, 0.f, 0.f, 0.f);
        if (row < N) {
            v = agg4[(size_t)row * 64 + x4];
            float nd = normI[row];
            v.x *= nd; v.y *= nd; v.z *= nd; v.w *= nd;
        }
        sA[r * 64 + (x4 ^ (r & 7))] = v;
    }

    // --- stage W: 2 mats x 3 gates x 16 cols x 128 k = 12288 floats,
    //     transposed into k-contiguous, XOR-swizzled slots ---
    float* sWs = (float*)sW;
#pragma unroll
    for (int i = 0; i < 48; ++i) {
        int f = i * 256 + tid;
        int c = f & 15;
        int k = (f >> 4) & 127;
        int gm = f >> 11;  // 0..5: 0..2 = Wi gates r,z,n; 3..5 = Wh gates
        const float* Wsrc = (gm < 3) ? Wi : Wh;
        int g = (gm < 3) ? gm : gm - 3;
        float w = Wsrc[k * 384 + g * 128 + cb * 16 + c];
        int rowW = gm * 16 + c;
        sWs[rowW * 128 + ((k >> 2) ^ (c & 7)) * 4 + (k & 3)] = w;
    }
    __syncthreads();

    const int tc = tid & 15;
    const int tr = tid >> 4;

    float acc[2][6];
#pragma unroll
    for (int i = 0; i < 2; ++i)
#pragma unroll
        for (int g = 0; g < 6; ++g) acc[i][g] = 0.f;

    for (int k4 = 0; k4 < 32; ++k4) {
        float4 w[6];
#pragma unroll
        for (int gm = 0; gm < 6; ++gm)
            w[gm] = sW[(gm * 16 + tc) * 32 + (k4 ^ (tc & 7))];
#pragma unroll
        for (int i = 0; i < 2; ++i) {
            int r = 2 * tr + i;
            int sl = k4 ^ (r & 7);
            float4 af = sA[r * 64 + sl];
            float4 ah = sA[r * 64 + 32 + sl];
#pragma unroll
            for (int g = 0; g < 3; ++g) {
                acc[i][g] += af.x * w[g].x + af.y * w[g].y + af.z * w[g].z + af.w * w[g].w;
                acc[i][3 + g] += ah.x * w[3 + g].x + ah.y * w[3 + g].y + ah.z * w[3 + g].z + ah.w * w[3 + g].w;
            }
        }
    }

    // --- epilogue: gates ---
    int col = cb * 16 + tc;
    float bir = bi[col], biz = bi[128 + col], bin = bi[256 + col];
    float bhr = bh[col], bhz = bh[128 + col], bhn = bh[256 + col];
#pragma unroll
    for (int i = 0; i < 2; ++i) {
        int row = nb * 32 + 2 * tr + i;
        if (row >= N) continue;
        float ir = acc[i][0] + bir, iz = acc[i][1] + biz, in_ = acc[i][2] + bin;
        float hr = acc[i][3] + bhr, hz = acc[i][4] + bhz, hn = acc[i][5] + bhn;
        float rg = 1.0f / (1.0f + __expf(-(ir + hr)));
        float zg = 1.0f / (1.0f + __expf(-(iz + hz)));
        float ng = tanhf(in_ + rg * hn);
        float hv = hx[(size_t)row * DIM + col];
        out[(size_t)row * DIM + col] = (1.0f - zg) * ng + zg * hv;
    }
}

// ---------------------------------------------------------------------------
extern "C" void kernel_launch(void* const* d_in, const int* in_sizes, int n_in,
                              void* d_out, int out_size, void* d_ws, size_t ws_size,
                              hipStream_t stream) {
    const float* feat = (const float*)d_in[0];
    const float* hx   = (const float*)d_in[1];
    const float* Wi   = (const float*)d_in[2];
    const float* bi   = (const float*)d_in[3];
    const float* Wh   = (const float*)d_in[4];
    const float* bh   = (const float*)d_in[5];
    const int* src    = (const int*)d_in[6];
    const int* dst    = (const int*)d_in[7];
    float* out        = (float*)d_out;

    const int N = in_sizes[0] / DIM;   // 50000
    const int E = in_sizes[6];         // 800000

    float* wsf  = (float*)d_ws;
    float* degO = wsf;            // N floats -> becomes norm_src
    float* degI = wsf + N;        // N floats -> becomes norm_dst
    float* agg  = wsf + 2 * N;    // N*256 floats

    // zero degrees + agg (ws is poisoned 0xAA before every call)
    hipMemsetAsync(d_ws, 0, (size_t)(2 * N + 256 * N) * sizeof(float), stream);

    deg_kernel<<<(E + 255) / 256, 256, 0, stream>>>(src, dst, degO, degI, E);
    norm_kernel<<<(2 * N + 255) / 256, 256, 0, stream>>>(wsf, 2 * N);
    scatter_kernel<<<(E + 3) / 4, 256, 0, stream>>>(
        (const float4*)feat, (const float4*)hx, src, dst, degO, agg, E);

    dim3 grid((N + 31) / 32, 8);
    gemm_gates_kernel<<<grid, 256, 0, stream>>>(agg, degI, Wi, bi, Wh, bh, hx, out, N);
}

// Round 3
// 514.164 us; speedup vs baseline: 6.1675x; 6.1675x over previous
//
#include <hip/hip_runtime.h>
#include <math.h>

#define DIM 128

typedef float f32x4v __attribute__((ext_vector_type(4)));
typedef short bf16x8 __attribute__((ext_vector_type(8)));

static __device__ __forceinline__ short f2bf(float f) {
    unsigned u = __float_as_uint(f);
    unsigned r = (u + 0x7fffu + ((u >> 16) & 1u)) >> 16;   // RNE
    return (short)r;
}

// ---------------------------------------------------------------------------
// K1: integer degree histogram.
__global__ __launch_bounds__(256) void deg_kernel(const int* __restrict__ src,
                                                  const int* __restrict__ dst,
                                                  int* degO, int* degI, int E) {
    int e = blockIdx.x * 256 + threadIdx.x;
    if (e < E) {
        atomicAdd(&degO[src[e]], 1);
        atomicAdd(&degI[dst[e]], 1);
    }
}

// K2: single-block exclusive scan of degI -> csrOff[N+1] + cursor copy.
__global__ __launch_bounds__(1024) void scan_kernel(const int* __restrict__ deg,
                                                    int* __restrict__ csrOff,
                                                    int* __restrict__ cursor, int N) {
    __shared__ int sh[1024];
    int t = threadIdx.x;
    int chunk = (N + 1023) >> 10;
    int lo = t * chunk;
    int hi = lo + chunk; if (hi > N) hi = N;
    int sum = 0;
    for (int i = lo; i < hi; ++i) sum += deg[i];
    sh[t] = sum;
    __syncthreads();
    for (int off = 1; off < 1024; off <<= 1) {
        int v = (t >= off) ? sh[t - off] : 0;
        __syncthreads();
        sh[t] += v;
        __syncthreads();
    }
    int run = (t > 0) ? sh[t - 1] : 0;
    for (int i = lo; i < hi; ++i) {
        csrOff[i] = run; cursor[i] = run;
        run += deg[i];
    }
    if (hi == N && lo <= N) { csrOff[N] = run; cursor[N] = run; }
}

// K3: int degree -> float rsqrt(max(deg,1)) in place (degO+degI).
__global__ __launch_bounds__(256) void norm_kernel(int* d, int n2) {
    int i = blockIdx.x * 256 + threadIdx.x;
    if (i < n2) {
        float c = (float)d[i];
        ((float*)d)[i] = rsqrtf(fmaxf(c, 1.0f));
    }
}

// K4: counting-sort fill: srcSorted grouped by dst.
__global__ __launch_bounds__(256) void fill_kernel(const int* __restrict__ src,
                                                   const int* __restrict__ dst,
                                                   int* cursor, int* __restrict__ srcSorted,
                                                   int E) {
    int e = blockIdx.x * 256 + threadIdx.x;
    if (e < E) {
        int pos = atomicAdd(&cursor[dst[e]], 1);
        srcSorted[pos] = src[e];
    }
}

// K5: pre-convert W to bf16, layout [cb][gm][n][k]: cb=out-col-chunk(8),
// gm=0..5 (Wi r,z,n then Wh r,z,n), n=col-in-chunk(16), k=0..127.
__global__ __launch_bounds__(256) void wconv_kernel(const float* __restrict__ Wi,
                                                    const float* __restrict__ Wh,
                                                    short* __restrict__ Wbf) {
    int i = blockIdx.x * 256 + threadIdx.x;     // 98304 total, exact grid
    int k = i & 127;
    int n = (i >> 7) & 15;
    int r = i >> 11;          // 0..47
    int gm = r % 6, cb = r / 6;
    const float* Wsrc = (gm < 3) ? Wi : Wh;
    int g = gm % 3;
    Wbf[i] = f2bf(Wsrc[k * 384 + g * 128 + cb * 16 + n]);
}

// ---------------------------------------------------------------------------
// K6: fused gather-aggregate + bf16 MFMA GEMM + GRU gates.
// Block: 256 threads (4 waves) x 64 nodes. Wave wv gathers rows wv*16..+15.
// sA: 64 rows x 264 shorts (256 k + pad) bf16. sW: 96 n-rows x 136 shorts.
__global__ __launch_bounds__(256, 2) void fused_kernel(
    const float* __restrict__ feat, const float* __restrict__ hx,
    const int* __restrict__ csrOff, const int* __restrict__ srcSorted,
    const float* __restrict__ normO, const float* __restrict__ normI,
    const short* __restrict__ Wbf,
    const float* __restrict__ bi, const float* __restrict__ bh,
    float* __restrict__ out, int N) {
    __shared__ __align__(16) short sA[64 * 264];
    __shared__ __align__(16) short sW[96 * 136];

    const int tid = threadIdx.x;
    const int wv = tid >> 6, lane = tid & 63;
    const int nb = blockIdx.x;

    // ---- phase 1: gather-aggregate into sA (bf16), norm folded ----
    const float4* feat4 = (const float4*)feat;
    const float4* hx4 = (const float4*)hx;
    const int half = lane >> 5, j = lane & 31;     // lane holds k = lane*4..+3
    const float4* base = half ? hx4 : feat4;
    for (int i = 0; i < 16; ++i) {
        int r = wv * 16 + i;
        int d = nb * 64 + r;
        float4 acc = make_float4(0.f, 0.f, 0.f, 0.f);
        if (d < N) {
            int beg = csrOff[d], end = csrOff[d + 1];
            #pragma unroll 4
            for (int e = beg; e < end; ++e) {
                int s = srcSorted[e];
                float ns = normO[s];
                float4 v = base[(size_t)s * 32 + j];
                acc.x += v.x * ns; acc.y += v.y * ns;
                acc.z += v.z * ns; acc.w += v.w * ns;
            }
            float nd = normI[d];
            acc.x *= nd; acc.y *= nd; acc.z *= nd; acc.w *= nd;
        }
        short4 p;
        p.x = f2bf(acc.x); p.y = f2bf(acc.y);
        p.z = f2bf(acc.z); p.w = f2bf(acc.w);
        *(short4*)&sA[r * 264 + lane * 4] = p;
    }
    __syncthreads();

    // ---- phase 2: 8 col-chunks of 16 output cols ----
    const int l15 = lane & 15;       // A-row m / B-col n / C-col
    const int quad = lane >> 4;
    const int wrb = wv * 16;         // wave's local row base

    for (int cb = 0; cb < 8; ++cb) {
        // stage 24KB bf16 weight slab (dense -> 272B padded rows)
        const short* Wsl = Wbf + cb * 12288;
        #pragma unroll
        for (int i = 0; i < 6; ++i) {
            int u = i * 256 + tid;   // 1536 x 16B units
            *(int4*)&sW[(u >> 4) * 136 + (u & 15) * 8] = *(const int4*)&Wsl[u * 8];
        }
        __syncthreads();

        f32x4v acc[6];
        #pragma unroll
        for (int g = 0; g < 6; ++g) acc[g] = (f32x4v){0.f, 0.f, 0.f, 0.f};

        #pragma unroll
        for (int kst = 0; kst < 4; ++kst) {
            const int ko = kst * 32 + quad * 8;
            bf16x8 aLo = *(const bf16x8*)&sA[(wrb + l15) * 264 + ko];
            bf16x8 aHi = *(const bf16x8*)&sA[(wrb + l15) * 264 + 128 + ko];
            #pragma unroll
            for (int g = 0; g < 3; ++g) {
                bf16x8 bI = *(const bf16x8*)&sW[(g * 16 + l15) * 136 + ko];
                acc[g] = __builtin_amdgcn_mfma_f32_16x16x32_bf16(aLo, bI, acc[g], 0, 0, 0);
                bf16x8 bH = *(const bf16x8*)&sW[((g + 3) * 16 + l15) * 136 + ko];
                acc[g + 3] = __builtin_amdgcn_mfma_f32_16x16x32_bf16(aHi, bH, acc[g + 3], 0, 0, 0);
            }
        }

        // epilogue: C/D layout col=lane&15, row=quad*4+reg
        int ocol = cb * 16 + l15;
        float bir = bi[ocol], biz = bi[128 + ocol], bin = bi[256 + ocol];
        float bhr = bh[ocol], bhz = bh[128 + ocol], bhn = bh[256 + ocol];
        #pragma unroll
        for (int reg = 0; reg < 4; ++reg) {
            int row = nb * 64 + wrb + quad * 4 + reg;
            if (row < N) {
                float ir = acc[0][reg] + bir, iz = acc[1][reg] + biz, in_ = acc[2][reg] + bin;
                float hr = acc[3][reg] + bhr, hz = acc[4][reg] + bhz, hn = acc[5][reg] + bhn;
                float rg = 1.0f / (1.0f + __expf(-(ir + hr)));
                float zg = 1.0f / (1.0f + __expf(-(iz + hz)));
                float ng = tanhf(in_ + rg * hn);
                float hv = hx[(size_t)row * DIM + ocol];
                out[(size_t)row * DIM + ocol] = (1.0f - zg) * ng + zg * hv;
            }
        }
        __syncthreads();   // protect sW before next restage
    }
}

// ---------------------------------------------------------------------------
extern "C" void kernel_launch(void* const* d_in, const int* in_sizes, int n_in,
                              void* d_out, int out_size, void* d_ws, size_t ws_size,
                              hipStream_t stream) {
    const float* feat = (const float*)d_in[0];
    const float* hx   = (const float*)d_in[1];
    const float* Wi   = (const float*)d_in[2];
    const float* bi   = (const float*)d_in[3];
    const float* Wh   = (const float*)d_in[4];
    const float* bh   = (const float*)d_in[5];
    const int* src    = (const int*)d_in[6];
    const int* dst    = (const int*)d_in[7];
    float* out        = (float*)d_out;

    const int N = in_sizes[0] / DIM;   // 50000
    const int E = in_sizes[6];         // 800000

    int* wsi = (int*)d_ws;
    int* degO      = wsi;                      // N  -> normO (float) after K3
    int* degI      = wsi + N;                  // N  -> normI (float) after K3
    int* csrOff    = wsi + 2 * N;              // N+1
    int* cursor    = wsi + 3 * N + 1;          // N+1
    int* srcSorted = wsi + 4 * N + 2;          // E
    size_t wofs = (((size_t)(4 * N + 2 + E)) * 4 + 15) & ~(size_t)15;
    short* Wbf = (short*)((char*)d_ws + wofs); // 98304 bf16 (~196KB)
    // total ws use: ~4.2 MB (vs proven-safe 51.6 MB budget)

    hipMemsetAsync(d_ws, 0, (size_t)(2 * N) * sizeof(int), stream);

    deg_kernel<<<(E + 255) / 256, 256, 0, stream>>>(src, dst, degO, degI, E);
    scan_kernel<<<1, 1024, 0, stream>>>(degI, csrOff, cursor, N);
    norm_kernel<<<(2 * N + 255) / 256, 256, 0, stream>>>(wsi, 2 * N);
    fill_kernel<<<(E + 255) / 256, 256, 0, stream>>>(src, dst, cursor, srcSorted, E);
    wconv_kernel<<<384, 256, 0, stream>>>(Wi, Wh, Wbf);

    fused_kernel<<<(N + 63) / 64, 256, 0, stream>>>(
        feat, hx, csrOff, srcSorted, (const float*)degO, (const float*)degI,
        Wbf, bi, bh, out, N);
}

// Round 4
// 402.936 us; speedup vs baseline: 7.8700x; 1.2760x over previous
//
#include <hip/hip_runtime.h>
#include <math.h>

#define DIM 128

typedef float f32x4v __attribute__((ext_vector_type(4)));
typedef short bf16x8 __attribute__((ext_vector_type(8)));

static __device__ __forceinline__ short f2bf(float f) {
    unsigned u = __float_as_uint(f);
    unsigned r = (u + 0x7fffu + ((u >> 16) & 1u)) >> 16;   // RNE
    return (short)r;
}
static __device__ __forceinline__ float bf2f(unsigned short s) {
    return __uint_as_float(((unsigned)s) << 16);
}

// ---------------------------------------------------------------------------
// K1: integer degree histogram.
__global__ __launch_bounds__(256) void deg_kernel(const int* __restrict__ src,
                                                  const int* __restrict__ dst,
                                                  int* degO, int* degI, int E) {
    int e = blockIdx.x * 256 + threadIdx.x;
    if (e < E) {
        atomicAdd(&degO[src[e]], 1);
        atomicAdd(&degI[dst[e]], 1);
    }
}

// ---------------------------------------------------------------------------
// K2a: per-block (1024 elems) sums of degI.
__global__ __launch_bounds__(256) void scan_bsum(const int* __restrict__ deg,
                                                 int* __restrict__ bsum, int N) {
    __shared__ int red[4];
    int b = blockIdx.x, t = threadIdx.x;
    int idx = b * 1024 + t * 4;
    int s = 0;
    if (idx + 3 < N) {
        int4 v = *(const int4*)&deg[idx];
        s = v.x + v.y + v.z + v.w;
    } else {
        for (int j = 0; j < 4; ++j) if (idx + j < N) s += deg[idx + j];
    }
    for (int off = 32; off; off >>= 1) s += __shfl_down(s, off);
    if ((t & 63) == 0) red[t >> 6] = s;
    __syncthreads();
    if (t == 0) bsum[b] = red[0] + red[1] + red[2] + red[3];
}

// K2b: one wave scans the <=64 block sums; exclusive prefixes + total.
__global__ __launch_bounds__(64) void scan_bpre(const int* __restrict__ bsum,
                                                int* __restrict__ bpre, int NB,
                                                int* csrOffN, int* cursorN) {
    int t = threadIdx.x;
    int own = (t < NB) ? bsum[t] : 0;
    int v = own;
    for (int off = 1; off < 64; off <<= 1) {
        int u = __shfl_up(v, off);
        if (t >= off) v += u;
    }
    if (t < NB) bpre[t] = v - own;
    if (t == 63) { *csrOffN = v; *cursorN = v; }
}

// K2c: per-block exclusive scan -> csrOff + cursor.
__global__ __launch_bounds__(256) void scan_off(const int* __restrict__ deg,
                                                const int* __restrict__ bpre,
                                                int* __restrict__ csrOff,
                                                int* __restrict__ cursor, int N) {
    __shared__ int sp[256];
    int b = blockIdx.x, t = threadIdx.x;
    int idx = b * 1024 + t * 4;
    int va[4];
    for (int j = 0; j < 4; ++j) va[j] = (idx + j < N) ? deg[idx + j] : 0;
    int s = va[0] + va[1] + va[2] + va[3];
    sp[t] = s;
    __syncthreads();
    for (int off = 1; off < 256; off <<= 1) {
        int u = (t >= off) ? sp[t - off] : 0;
        __syncthreads();
        sp[t] += u;
        __syncthreads();
    }
    int o = bpre[b] + sp[t] - s;
    for (int j = 0; j < 4; ++j) {
        if (idx + j < N) { csrOff[idx + j] = o; cursor[idx + j] = o; }
        o += va[j];
    }
}

// ---------------------------------------------------------------------------
// K3: int degree -> float rsqrt(max(deg,1)) in place (degO+degI).
__global__ __launch_bounds__(256) void norm_kernel(int* d, int n2) {
    int i = blockIdx.x * 256 + threadIdx.x;
    if (i < n2) {
        float c = (float)d[i];
        ((float*)d)[i] = rsqrtf(fmaxf(c, 1.0f));
    }
}

// ---------------------------------------------------------------------------
// K4: feathx[n][0..127]=feat*normO, [128..255]=hx*normO, bf16.
__global__ __launch_bounds__(256) void xconv_kernel(const float* __restrict__ feat,
                                                    const float* __restrict__ hx,
                                                    const float* __restrict__ normO,
                                                    short* __restrict__ fh, int N) {
    int i = blockIdx.x * 256 + threadIdx.x;
    if (i >= N * 64) return;
    int n = i >> 6, q = i & 63;
    float ns = normO[n];
    const float* sp = (q < 32) ? &feat[(size_t)n * 128 + q * 4]
                               : &hx[(size_t)n * 128 + (q - 32) * 4];
    float4 v = *(const float4*)sp;
    short4 p;
    p.x = f2bf(v.x * ns); p.y = f2bf(v.y * ns);
    p.z = f2bf(v.z * ns); p.w = f2bf(v.w * ns);
    *(short4*)&fh[(size_t)n * 256 + q * 4] = p;   // q*4 == 128+(q-32)*4 for q>=32
}

// ---------------------------------------------------------------------------
// K5: counting-sort fill: srcSorted grouped by dst.
__global__ __launch_bounds__(256) void fill_kernel(const int* __restrict__ src,
                                                   const int* __restrict__ dst,
                                                   int* cursor, int* __restrict__ srcSorted,
                                                   int E) {
    int e = blockIdx.x * 256 + threadIdx.x;
    if (e < E) {
        int pos = atomicAdd(&cursor[dst[e]], 1);
        srcSorted[pos] = src[e];
    }
}

// ---------------------------------------------------------------------------
// K6: W -> bf16, layout [cb][gm][n][k].
__global__ __launch_bounds__(256) void wconv_kernel(const float* __restrict__ Wi,
                                                    const float* __restrict__ Wh,
                                                    short* __restrict__ Wbf) {
    int i = blockIdx.x * 256 + threadIdx.x;     // 98304 total
    int k = i & 127;
    int n = (i >> 7) & 15;
    int r = i >> 11;
    int gm = r % 6, cb = r / 6;
    const float* Wsrc = (gm < 3) ? Wi : Wh;
    int g = gm % 3;
    Wbf[i] = f2bf(Wsrc[k * 384 + g * 128 + cb * 16 + n]);
}

// ---------------------------------------------------------------------------
// K7: fused gather-aggregate + bf16 MFMA GEMM + GRU gates.
// 256 threads = 4 waves x 64 nodes; LDS only sA (33.8KB) -> 4 blocks/CU.
// B-fragments load straight from L2-resident Wbf.
__global__ __launch_bounds__(256, 4) void fused_kernel(
    const short* __restrict__ fh, const float* __restrict__ hx,
    const int* __restrict__ csrOff, const int* __restrict__ srcSorted,
    const float* __restrict__ normI, const short* __restrict__ Wbf,
    const float* __restrict__ bi, const float* __restrict__ bh,
    float* __restrict__ out, int N) {
    __shared__ __align__(16) short sA[64 * 264];

    const int tid = threadIdx.x;
    const int wv = tid >> 6, lane = tid & 63;
    const int nb = blockIdx.x;
    const ushort4* fh4 = (const ushort4*)fh;

    // ---- phase 1: gather pre-scaled bf16 rows; one 8B load/lane/edge ----
    for (int i = 0; i < 16; ++i) {
        int r = wv * 16 + i;
        int d = nb * 64 + r;
        float4 acc = make_float4(0.f, 0.f, 0.f, 0.f);
        if (d < N) {
            int beg = csrOff[d], end = csrOff[d + 1];
            #pragma unroll 4
            for (int e = beg; e < end; ++e) {
                int s = srcSorted[e];
                ushort4 v = fh4[(size_t)s * 64 + lane];
                acc.x += bf2f(v.x); acc.y += bf2f(v.y);
                acc.z += bf2f(v.z); acc.w += bf2f(v.w);
            }
            float nd = normI[d];
            acc.x *= nd; acc.y *= nd; acc.z *= nd; acc.w *= nd;
        }
        short4 p;
        p.x = f2bf(acc.x); p.y = f2bf(acc.y);
        p.z = f2bf(acc.z); p.w = f2bf(acc.w);
        *(short4*)&sA[r * 264 + lane * 4] = p;
    }
    __syncthreads();

    // ---- phase 2: 8 col-chunks, MFMA, gates ----
    const int l15 = lane & 15, quad = lane >> 4;
    const int wrb = wv * 16;
    const short* aRow = &sA[(wrb + l15) * 264];

    for (int cb = 0; cb < 8; ++cb) {
        f32x4v acc[6];
        #pragma unroll
        for (int g = 0; g < 6; ++g) acc[g] = (f32x4v){0.f, 0.f, 0.f, 0.f};

        #pragma unroll
        for (int kst = 0; kst < 4; ++kst) {
            const int ko = kst * 32 + quad * 8;
            bf16x8 aLo = *(const bf16x8*)&aRow[ko];
            bf16x8 aHi = *(const bf16x8*)&aRow[128 + ko];
            const short* wb = Wbf + cb * 12288 + l15 * 128 + ko;
            #pragma unroll
            for (int g = 0; g < 3; ++g) {
                bf16x8 bI = *(const bf16x8*)&wb[g * 2048];
                acc[g] = __builtin_amdgcn_mfma_f32_16x16x32_bf16(aLo, bI, acc[g], 0, 0, 0);
                bf16x8 bH = *(const bf16x8*)&wb[(g + 3) * 2048];
                acc[g + 3] = __builtin_amdgcn_mfma_f32_16x16x32_bf16(aHi, bH, acc[g + 3], 0, 0, 0);
            }
        }

        int ocol = cb * 16 + l15;
        float bir = bi[ocol], biz = bi[128 + ocol], bin = bi[256 + ocol];
        float bhr = bh[ocol], bhz = bh[128 + ocol], bhn = bh[256 + ocol];
        #pragma unroll
        for (int reg = 0; reg < 4; ++reg) {
            int row = nb * 64 + wrb + quad * 4 + reg;
            if (row < N) {
                float ir = acc[0][reg] + bir, iz = acc[1][reg] + biz, in_ = acc[2][reg] + bin;
                float hr = acc[3][reg] + bhr, hz = acc[4][reg] + bhz, hn = acc[5][reg] + bhn;
                float rg = 1.0f / (1.0f + __expf(-(ir + hr)));
                float zg = 1.0f / (1.0f + __expf(-(iz + hz)));
                float ng = tanhf(in_ + rg * hn);
                float hv = hx[(size_t)row * DIM + ocol];
                out[(size_t)row * DIM + ocol] = (1.0f - zg) * ng + zg * hv;
            }
        }
    }
}

// ---------------------------------------------------------------------------
extern "C" void kernel_launch(void* const* d_in, const int* in_sizes, int n_in,
                              void* d_out, int out_size, void* d_ws, size_t ws_size,
                              hipStream_t stream) {
    const float* feat = (const float*)d_in[0];
    const float* hx   = (const float*)d_in[1];
    const float* Wi   = (const float*)d_in[2];
    const float* bi   = (const float*)d_in[3];
    const float* Wh   = (const float*)d_in[4];
    const float* bh   = (const float*)d_in[5];
    const int* src    = (const int*)d_in[6];
    const int* dst    = (const int*)d_in[7];
    float* out        = (float*)d_out;

    const int N = in_sizes[0] / DIM;   // 50000
    const int E = in_sizes[6];         // 800000
    const int NB = (N + 1023) / 1024;  // 49 (<=64 required by scan_bpre)

    int* wsi = (int*)d_ws;
    int* degO      = wsi;                      // N  -> normO (float) after K3
    int* degI      = wsi + N;                  // N  -> normI (float) after K3
    int* csrOff    = wsi + 2 * N;              // N+1
    int* cursor    = wsi + 3 * N + 1;          // N+1
    int* srcSorted = wsi + 4 * N + 2;          // E
    int* bsum      = wsi + 4 * N + 2 + E;      // NB
    int* bpre      = bsum + NB;                // NB
    size_t wofs = (((size_t)(4 * N + 2 + E + 2 * NB)) * 4 + 15) & ~(size_t)15;
    short* Wbf = (short*)((char*)d_ws + wofs);         // 98304 bf16
    size_t fofs = (wofs + 98304 * 2 + 15) & ~(size_t)15;
    short* fh = (short*)((char*)d_ws + fofs);          // N*256 bf16 (~25.6MB)
    // total ws: ~29.9 MB (proven-safe budget: 51.6 MB)

    hipMemsetAsync(d_ws, 0, (size_t)(2 * N) * sizeof(int), stream);

    deg_kernel<<<(E + 255) / 256, 256, 0, stream>>>(src, dst, degO, degI, E);
    scan_bsum<<<NB, 256, 0, stream>>>(degI, bsum, N);
    scan_bpre<<<1, 64, 0, stream>>>(bsum, bpre, NB, &csrOff[N], &cursor[N]);
    scan_off<<<NB, 256, 0, stream>>>(degI, bpre, csrOff, cursor, N);
    norm_kernel<<<(2 * N + 255) / 256, 256, 0, stream>>>(wsi, 2 * N);
    xconv_kernel<<<(N * 64 + 255) / 256, 256, 0, stream>>>(
        feat, hx, (const float*)degO, fh, N);
    fill_kernel<<<(E + 255) / 256, 256, 0, stream>>>(src, dst, cursor, srcSorted, E);
    wconv_kernel<<<384, 256, 0, stream>>>(Wi, Wh, Wbf);

    fused_kernel<<<(N + 63) / 64, 256, 0, stream>>>(
        fh, hx, csrOff, srcSorted, (const float*)degI, Wbf, bi, bh, out, N);
}